// Round 9
// baseline (89.933 us; speedup 1.0000x reference)
//
#include <hip/hip_runtime.h>

// Sinkhorn on 8192 independent 64x64 f32 matrices, TWO waves per matrix.
// R4/R8 structure, plus: rK/cK are pinned into VGPRs with an empty
// asm volatile("":"+v") after the exp. R4/R8 showed VGPR_Count=52 < 64
// live K floats with no scratch traffic -> the compiler was re-loading K
// from cache inside the 20-iter loop (address-calc VALU bloat + VMEM
// stalls). Opaque asm makes re-materialization illegal; launch_bounds
// (128,2) caps VGPR at 256 so it need not spill.
// Wave h (h=0,1) holds:
//   rK[k] = A[lane][32h+k]   (row `lane`, its column-half)  -> partial K*v
//   cK[i] = A[32h+i][lane]   (col `lane`, its row-half)     -> partial K^T*u
// u/v stored ROTATED (lane l holds index (l+32h)&63) so readlane indices
// are literals 0..31. Per matvec: 32 RL + 32 FMA, one LDS exchange, 1 barrier.

static constexpr int   kIters = 20;
static constexpr float kEps   = 1e-6f;

__device__ __forceinline__ float RLf(float x, int l) {
    return __int_as_float(__builtin_amdgcn_readlane(__float_as_int(x), l));
}

__global__ __launch_bounds__(128, 2) void sinkhorn64_pin(const float* __restrict__ in,
                                                         float* __restrict__ out) {
    __shared__ float xb0[2][64];   // exchange buffer 0  [half][lane]
    __shared__ float xb1[2][64];   // exchange buffer 1
    const int tid  = threadIdx.x;
    const int h    = tid >> 6;               // which half this wave owns
    const int lane = tid & 63;
    const int c    = (lane + 32 * h) & 63;   // rotated index (self-inverse)
    const long m   = blockIdx.x;             // matrix 0..8191
    const float* __restrict__ A = in  + m * 4096;
    float* __restrict__ O       = out + m * 4096;

    // cK[i] = A[32h+i][lane]  (32 coalesced 256B loads)
    float cK[32];
#pragma unroll
    for (int i = 0; i < 32; ++i) cK[i] = A[((32 * h + i) << 6) + lane];

    // rK[k] = A[lane][32h+k]  (8 x float4 per lane; lines hot from cK pass)
    float rK[32];
#pragma unroll
    for (int k4 = 0; k4 < 8; ++k4) {
        const float4 f = *reinterpret_cast<const float4*>(A + (lane << 6) + 32 * h + (k4 << 2));
        rK[4 * k4 + 0] = f.x; rK[4 * k4 + 1] = f.y;
        rK[4 * k4 + 2] = f.z; rK[4 * k4 + 3] = f.w;
    }

    // Row max: own-half partial, exchange, combine (both plain and rotated).
    float pm = rK[0];
#pragma unroll
    for (int k = 1; k < 32; ++k) pm = fmaxf(pm, rK[k]);
    xb0[h][lane] = pm;
    __syncthreads();
    const float mx  = fmaxf(pm, xb0[1 - h][lane]);   // max of row `lane`
    const float mxr = fmaxf(xb0[0][c], xb0[1][c]);   // max of row `c`

#pragma unroll
    for (int k = 0; k < 32; ++k) rK[k] = __expf(rK[k] - mx);
#pragma unroll
    for (int i = 0; i < 32; ++i) cK[i] = __expf(cK[i] - RLf(mxr, i));

    // Pin all K values into VGPRs: opaque to the optimizer, so it cannot
    // re-load them from A inside the loop.
#pragma unroll
    for (int k = 0; k < 32; ++k) {
        asm volatile("" : "+v"(rK[k]));
        asm volatile("" : "+v"(cK[k]));
    }

    // Rotated scaling vectors: lane holds u_c, v_c.
    float ur = 1.0f, vr = 1.0f;

#pragma unroll 1
    for (int it = 0; it < kIters; ++it) {
        // partial (K v)_{row=lane} over own columns; v[32h+k] = lane k of vr
        float a0 = 0.f, a1 = 0.f, a2 = 0.f, a3 = 0.f;
#pragma unroll
        for (int k = 0; k < 32; k += 4) {
            a0 = fmaf(RLf(vr, k + 0), rK[k + 0], a0);
            a1 = fmaf(RLf(vr, k + 1), rK[k + 1], a1);
            a2 = fmaf(RLf(vr, k + 2), rK[k + 2], a2);
            a3 = fmaf(RLf(vr, k + 3), rK[k + 3], a3);
        }
        xb1[h][lane] = (a0 + a1) + (a2 + a3);
        __syncthreads();
        const float w = xb1[0][c] + xb1[1][c];            // w for row c
        ur = ur * __builtin_amdgcn_rcpf(fmaf(ur, w, kEps));

        // partial (K^T u)_{col=lane} over own rows; u[32h+i] = lane i of ur
        float b0 = 0.f, b1 = 0.f, b2 = 0.f, b3 = 0.f;
#pragma unroll
        for (int i = 0; i < 32; i += 4) {
            b0 = fmaf(RLf(ur, i + 0), cK[i + 0], b0);
            b1 = fmaf(RLf(ur, i + 1), cK[i + 1], b1);
            b2 = fmaf(RLf(ur, i + 2), cK[i + 2], b2);
            b3 = fmaf(RLf(ur, i + 3), cK[i + 3], b3);
        }
        xb0[h][lane] = (b0 + b1) + (b2 + b3);
        __syncthreads();
        const float t = xb0[0][c] + xb0[1][c];            // t for col c
        vr = vr * __builtin_amdgcn_rcpf(fmaf(vr, t, kEps));
    }

    // Unrotate v: wave0's vr is already identity layout.
    xb1[h][lane] = vr;
    __syncthreads();
    const float vfin = xb1[0][lane];

    // O[32h+i][lane] = u_{32h+i} * K[32h+i][lane] * v_lane  (coalesced)
#pragma unroll
    for (int i = 0; i < 32; ++i) {
        O[((32 * h + i) << 6) + lane] = RLf(ur, i) * cK[i] * vfin;
    }
}

extern "C" void kernel_launch(void* const* d_in, const int* in_sizes, int n_in,
                              void* d_out, int out_size, void* d_ws, size_t ws_size,
                              hipStream_t stream) {
    const float* in = (const float*)d_in[0];
    float* out      = (float*)d_out;
    // One matrix per 128-thread (2-wave) block.
    sinkhorn64_pin<<<8192, 128, 0, stream>>>(in, out);
}

// Round 10
// 87.290 us; speedup vs baseline: 1.0303x; 1.0303x over previous
//
#include <hip/hip_runtime.h>

// Sinkhorn on 8192 independent 64x64 f32 matrices.
// 256-thread blocks = 4 waves = TWO independent matrices, each handled by
// its own 2-wave pair in the R4 structure (best instruction economy:
// per matvec 32 RL + 32 FMA per wave, one LDS exchange, one barrier).
// Why: measured occupancy is ~6 blocks/CU regardless of block size
// (128-thr -> 37%, 256-thr -> 74%), so packing 2 matrices per block
// doubles resident waves at identical per-matrix instruction count.
// Wave pair p (p=0,1 -> matrix 2*blockIdx+p), wave half h:
//   rK[k] = A[lane][32h+k]  (row `lane`, column-half)  -> partial K*v
//   cK[i] = A[32h+i][lane]  (col `lane`, row-half)     -> partial K^T*u
// u/v stored ROTATED (lane l holds index (l+32h)&63) so readlane indices
// are literals 0..31.

static constexpr int   kIters = 20;
static constexpr float kEps   = 1e-6f;

__device__ __forceinline__ float RLf(float x, int l) {
    return __int_as_float(__builtin_amdgcn_readlane(__float_as_int(x), l));
}

__global__ __launch_bounds__(256) void sinkhorn64_2m(const float* __restrict__ in,
                                                     float* __restrict__ out) {
    __shared__ float xb0[2][2][64];   // [matrix-pair][half][lane]
    __shared__ float xb1[2][2][64];
    const int tid  = threadIdx.x;
    const int wid  = tid >> 6;
    const int p    = wid >> 1;               // which matrix in this block
    const int h    = wid & 1;                // which half this wave owns
    const int lane = tid & 63;
    const int c    = (lane + 32 * h) & 63;   // rotated index (self-inverse)
    const long m   = (long)blockIdx.x * 2 + p;   // matrix 0..8191
    const float* __restrict__ A = in  + m * 4096;
    float* __restrict__ O       = out + m * 4096;

    // cK[i] = A[32h+i][lane]  (32 coalesced 256B loads)
    float cK[32];
#pragma unroll
    for (int i = 0; i < 32; ++i) cK[i] = A[((32 * h + i) << 6) + lane];

    // rK[k] = A[lane][32h+k]  (8 x float4 per lane; lines hot from cK pass)
    float rK[32];
#pragma unroll
    for (int k4 = 0; k4 < 8; ++k4) {
        const float4 f = *reinterpret_cast<const float4*>(A + (lane << 6) + 32 * h + (k4 << 2));
        rK[4 * k4 + 0] = f.x; rK[4 * k4 + 1] = f.y;
        rK[4 * k4 + 2] = f.z; rK[4 * k4 + 3] = f.w;
    }

    // Row max: own-half partial, exchange, combine (plain and rotated).
    float pm = rK[0];
#pragma unroll
    for (int k = 1; k < 32; ++k) pm = fmaxf(pm, rK[k]);
    xb0[p][h][lane] = pm;
    __syncthreads();
    const float mx  = fmaxf(pm, xb0[p][1 - h][lane]);      // max of row `lane`
    const float mxr = fmaxf(xb0[p][0][c], xb0[p][1][c]);   // max of row `c`

#pragma unroll
    for (int k = 0; k < 32; ++k) rK[k] = __expf(rK[k] - mx);
#pragma unroll
    for (int i = 0; i < 32; ++i) cK[i] = __expf(cK[i] - RLf(mxr, i));

    // Rotated scaling vectors: lane holds u_c, v_c.
    float ur = 1.0f, vr = 1.0f;

#pragma unroll 1
    for (int it = 0; it < kIters; ++it) {
        // partial (K v)_{row=lane} over own columns; v[32h+k] = lane k of vr
        float a0 = 0.f, a1 = 0.f, a2 = 0.f, a3 = 0.f;
#pragma unroll
        for (int k = 0; k < 32; k += 4) {
            a0 = fmaf(RLf(vr, k + 0), rK[k + 0], a0);
            a1 = fmaf(RLf(vr, k + 1), rK[k + 1], a1);
            a2 = fmaf(RLf(vr, k + 2), rK[k + 2], a2);
            a3 = fmaf(RLf(vr, k + 3), rK[k + 3], a3);
        }
        xb1[p][h][lane] = (a0 + a1) + (a2 + a3);
        __syncthreads();
        const float w = xb1[p][0][c] + xb1[p][1][c];          // w for row c
        ur = ur * __builtin_amdgcn_rcpf(fmaf(ur, w, kEps));

        // partial (K^T u)_{col=lane} over own rows; u[32h+i] = lane i of ur
        float b0 = 0.f, b1 = 0.f, b2 = 0.f, b3 = 0.f;
#pragma unroll
        for (int i = 0; i < 32; i += 4) {
            b0 = fmaf(RLf(ur, i + 0), cK[i + 0], b0);
            b1 = fmaf(RLf(ur, i + 1), cK[i + 1], b1);
            b2 = fmaf(RLf(ur, i + 2), cK[i + 2], b2);
            b3 = fmaf(RLf(ur, i + 3), cK[i + 3], b3);
        }
        xb0[p][h][lane] = (b0 + b1) + (b2 + b3);
        __syncthreads();
        const float t = xb0[p][0][c] + xb0[p][1][c];          // t for col c
        vr = vr * __builtin_amdgcn_rcpf(fmaf(vr, t, kEps));
    }

    // Unrotate v: wave h=0 of this pair holds identity layout.
    xb1[p][h][lane] = vr;
    __syncthreads();
    const float vfin = xb1[p][0][lane];

    // O[32h+i][lane] = u_{32h+i} * K[32h+i][lane] * v_lane  (coalesced)
#pragma unroll
    for (int i = 0; i < 32; ++i) {
        O[((32 * h + i) << 6) + lane] = RLf(ur, i) * cK[i] * vfin;
    }
}

extern "C" void kernel_launch(void* const* d_in, const int* in_sizes, int n_in,
                              void* d_out, int out_size, void* d_ws, size_t ws_size,
                              hipStream_t stream) {
    const float* in = (const float*)d_in[0];
    float* out      = (float*)d_out;
    // 8192 matrices, 2 matrices per 256-thread (4-wave) block.
    sinkhorn64_2m<<<4096, 256, 0, stream>>>(in, out);
}